// Round 7
// baseline (1264.306 us; speedup 1.0000x reference)
//
#include <hip/hip_runtime.h>

// SGC-Res: out = LayerNorm( (A @ feat) @ W^T + b )
// Identity: (A @ F) @ W^T = A @ (F @ W^T) = A @ G (G in bf16).
// R7: the whole CSR-build + gemm pipeline is ONE co-resident mega-kernel
// (grid=1024, __launch_bounds__(256,4) -> 4 wg/CU guaranteed co-resident)
// with manual device-scope grid barriers between phases:
//   P0 bucket-hist (bucket-major hist2d)  | B1
//   P1 per-bucket scan across blocks      | B2
//   P2 bucket-total scan (block 0)        | B3
//   P3 bucket scatter -> epair1           | B4
//   P4 per-bucket row regroup -> epair2 + offs2 | B5
//   P5 gemm G(bf16) = F @ W^T   (G overwrites epair1 - dead by then)
// Then k_node (unchanged from R6, proven 57us) as a second launch.

typedef unsigned int u32;
typedef unsigned short u16;
typedef unsigned long long u64;
#define RFL(x) __builtin_amdgcn_readfirstlane(x)

#define GRID 1024   // must stay <= 4 wg/CU * 256 CU (co-residency)
#define MAXBK 2048  // bucket capacity in LDS (N <= 131072)

__device__ __forceinline__ float bf2f(u16 v) {
    return __uint_as_float((u32)v << 16);
}
__device__ __forceinline__ u16 f2bf(float f) {
    u32 b = __float_as_uint(f);
    return (u16)((b + 0x7FFFu + ((b >> 16) & 1u)) >> 16);  // RNE
}

// Grid-wide barrier. Safe ONLY because all GRID blocks are co-resident.
__device__ __forceinline__ void gbar(u32* cnt, u32 target) {
    __syncthreads();
    if (threadIdx.x == 0) {
        __threadfence();  // make prior global writes visible device-wide
        __hip_atomic_fetch_add(cnt, 1u, __ATOMIC_RELEASE,
                               __HIP_MEMORY_SCOPE_AGENT);
        while (__hip_atomic_load(cnt, __ATOMIC_ACQUIRE,
                                 __HIP_MEMORY_SCOPE_AGENT) < target)
            __builtin_amdgcn_s_sleep(8);
        __threadfence();
    }
    __syncthreads();
}

__device__ __forceinline__ u32 blk_scan256(u32 v, u32* wsum, u32& total) {
    int lane = threadIdx.x & 63, wid = threadIdx.x >> 6;
    u32 incl = v;
#pragma unroll
    for (int o = 1; o < 64; o <<= 1) {
        u32 u = __shfl_up(incl, o);
        if (lane >= o) incl += u;
    }
    if (lane == 63) wsum[wid] = incl;
    __syncthreads();
    u32 woff = 0;
    for (int w = 0; w < wid; ++w) woff += wsum[w];
    total = wsum[0] + wsum[1] + wsum[2] + wsum[3];
    __syncthreads();
    return woff + incl - v;  // exclusive prefix
}

__global__ __launch_bounds__(256, 4) void k_mega(
    const float* __restrict__ feat, const int* __restrict__ row,
    const int* __restrict__ col, const float* __restrict__ vals,
    const float* __restrict__ W,
    u16* __restrict__ G, u64* __restrict__ epair1, u64* __restrict__ epair2,
    u32* __restrict__ hist2d, u32* __restrict__ btot, u32* __restrict__ bbase,
    u32* __restrict__ offs2, u32* __restrict__ bar,
    int N, int E, int NBK, int CH)
{
    __shared__ __align__(16) u32 smem[4164];  // 16,656 B: max(fs 16KB, 2*NBK)
    int tid = threadIdx.x;
    int blk = blockIdx.x;
    int lane = tid & 63, wid = tid >> 6;
    u32* wsum = smem + 4160;

    int e0 = blk * CH;
    int e1 = e0 + CH; if (e1 > E) e1 = E;   // CH,E mult of 4 -> quads tile

    // ---------- P0: bucket histogram of this block's edge chunk ----------
    for (int i = tid; i < NBK; i += 256) smem[i] = 0;
    __syncthreads();
    for (int i = e0 + tid * 4; i + 4 <= e1; i += 1024) {
        int4 r = *reinterpret_cast<const int4*>(&row[i]);
        atomicAdd(&smem[(u32)r.x >> 6], 1u);
        atomicAdd(&smem[(u32)r.y >> 6], 1u);
        atomicAdd(&smem[(u32)r.z >> 6], 1u);
        atomicAdd(&smem[(u32)r.w >> 6], 1u);
    }
    __syncthreads();
    for (int i = tid; i < NBK; i += 256)          // bucket-major store
        hist2d[(size_t)i * GRID + blk] = smem[i];
    gbar(bar, 1 * GRID);

    // ---------- P1: per-bucket exclusive scan across the GRID blocks -----
    for (int bkt = blk; bkt < NBK; bkt += GRID) {
        u32* hrow = hist2d + (size_t)bkt * GRID;
        u32 carry = 0;
        for (int r = 0; r < GRID; r += 256) {     // coalesced
            u32 tot;
            u32 ex = blk_scan256(hrow[r + tid], wsum, tot);
            hrow[r + tid] = ex + carry;
            carry += tot;
        }
        if (tid == 0) btot[bkt] = carry;
    }
    gbar(bar, 2 * GRID);

    // ---------- P2: scan bucket totals (block 0 only) ---------------------
    if (blk == 0) {
        u32 carry = 0;
        for (int r = 0; r < NBK; r += 256) {
            int i = r + tid;
            u32 v = (i < NBK) ? btot[i] : 0;
            u32 tot;
            u32 ex = blk_scan256(v, wsum, tot);
            if (i < NBK) bbase[i] = ex + carry;
            carry += tot;
        }
        if (tid == 0) bbase[NBK] = (u32)E;
    }
    gbar(bar, 3 * GRID);

    // ---------- P3: scatter edges to bucket-ordered epair1 ----------------
    {
        u32* lbase = smem;          // NBK
        u32* lcnt  = smem + NBK;    // NBK  (2*NBK <= 4096 <= 4160)
        for (int i = tid; i < NBK; i += 256) {
            lbase[i] = bbase[i] + hist2d[(size_t)i * GRID + blk];
            lcnt[i] = 0;
        }
        __syncthreads();
        for (int i = e0 + tid * 4; i + 4 <= e1; i += 1024) {
            int4 r = *reinterpret_cast<const int4*>(&row[i]);
            int4 c = *reinterpret_cast<const int4*>(&col[i]);
            float4 v = *reinterpret_cast<const float4*>(&vals[i]);
            u32 k0 = (u32)r.x >> 6, k1 = (u32)r.y >> 6;
            u32 k2 = (u32)r.z >> 6, k3 = (u32)r.w >> 6;
            u32 q0 = atomicAdd(&lcnt[k0], 1u);
            u32 q1 = atomicAdd(&lcnt[k1], 1u);
            u32 q2 = atomicAdd(&lcnt[k2], 1u);
            u32 q3 = atomicAdd(&lcnt[k3], 1u);
            epair1[lbase[k0] + q0] = (u64)((u32)c.x | (((u32)r.x & 63u) << 26))
                                   | ((u64)__float_as_uint(v.x) << 32);
            epair1[lbase[k1] + q1] = (u64)((u32)c.y | (((u32)r.y & 63u) << 26))
                                   | ((u64)__float_as_uint(v.y) << 32);
            epair1[lbase[k2] + q2] = (u64)((u32)c.z | (((u32)r.z & 63u) << 26))
                                   | ((u64)__float_as_uint(v.z) << 32);
            epair1[lbase[k3] + q3] = (u64)((u32)c.w | (((u32)r.w & 63u) << 26))
                                   | ((u64)__float_as_uint(v.w) << 32);
        }
    }
    gbar(bar, 4 * GRID);

    // ---------- P4: per-bucket regroup by local row -> CSR epair2 ---------
    {
        u32* cnt  = smem;        // 64
        u32* base = smem + 64;   // 64
        u32* cnt2 = smem + 128;  // 64
        if (blk == 0 && tid == 0) offs2[N] = (u32)E;
        for (int bkt = blk; bkt < NBK; bkt += GRID) {
            if (tid < 64) { cnt[tid] = 0; cnt2[tid] = 0; }
            __syncthreads();
            int s = RFL((int)bbase[bkt]);
            int t = RFL((int)bbase[bkt + 1]);
            const u32* meta1 = (const u32*)epair1;
            for (int i = s + tid; i < t; i += 256)
                atomicAdd(&cnt[meta1[2 * (size_t)i] >> 26], 1u);
            __syncthreads();
            if (tid < 64) {
                u32 v = cnt[tid];
                u32 incl = v;
#pragma unroll
                for (int o = 1; o < 64; o <<= 1) {
                    u32 u = __shfl_up(incl, o);
                    if (tid >= o) incl += u;
                }
                u32 ex = incl - v;
                base[tid] = ex;
                int n = (bkt << 6) + tid;
                if (n < N) offs2[n] = (u32)s + ex;
            }
            __syncthreads();
            for (int i = s + tid; i < t; i += 256) {
                u64 p = epair1[i];
                u32 m = (u32)p;
                u32 rnk = atomicAdd(&cnt2[m >> 26], 1u);
                epair2[(size_t)s + base[m >> 26] + rnk] =
                    (p & 0xFFFFFFFF00000000ull) | (u64)(m & 0x03FFFFFFu);
            }
            __syncthreads();
        }
    }
    gbar(bar, 5 * GRID);

    // ---------- P5: G(bf16) = F @ W^T  (overwrites epair1 region) ---------
    {
        float* fs = (float*)smem;   // 4096 floats
        float wr[64];
#pragma unroll
        for (int d4 = 0; d4 < 16; ++d4) {
            float4 w4 = *reinterpret_cast<const float4*>(&W[lane * 64 + d4 * 4]);
            wr[d4 * 4 + 0] = w4.x; wr[d4 * 4 + 1] = w4.y;
            wr[d4 * 4 + 2] = w4.z; wr[d4 * 4 + 3] = w4.w;
        }
        for (int t0 = blk; t0 < NBK; t0 += GRID) {
            int n0 = t0 * 64;
            int valid = N - n0; if (valid > 64) valid = 64;
            int elems = valid * 64;
            __syncthreads();
            for (int idx = tid * 4; idx < elems; idx += 1024)
                *reinterpret_cast<float4*>(&fs[idx]) =
                    *reinterpret_cast<const float4*>(&feat[(size_t)n0 * 64 + idx]);
            __syncthreads();
            for (int j = 0; j < 16; ++j) {
                int r = wid * 16 + j;
                if (r >= valid) break;
                float o = 0.f;
#pragma unroll
                for (int d4 = 0; d4 < 16; ++d4) {
                    float4 h4 = *reinterpret_cast<const float4*>(&fs[r * 64 + d4 * 4]);
                    o = fmaf(h4.x, wr[d4 * 4 + 0], o);
                    o = fmaf(h4.y, wr[d4 * 4 + 1], o);
                    o = fmaf(h4.z, wr[d4 * 4 + 2], o);
                    o = fmaf(h4.w, wr[d4 * 4 + 3], o);
                }
                G[(size_t)(n0 + r) * 64 + lane] = f2bf(o);
            }
        }
    }
}

// One 64-lane wave per node, lane = class c. UNCHANGED from R6 (proven).
__global__ __launch_bounds__(256) void k_node(
    const u16* __restrict__ G, const u64* __restrict__ epair2,
    const u32* __restrict__ offs2, const float* __restrict__ bias,
    const float* __restrict__ gamma, const float* __restrict__ beta,
    float* __restrict__ out, int N)
{
    int lane = threadIdx.x & 63;
    int n = (blockIdx.x << 2) + (threadIdx.x >> 6);
    if (n >= N) return;
    int start = RFL((int)offs2[n]);
    int end   = RFL((int)offs2[n + 1]);

    float acc0 = 0.f, acc1 = 0.f;
    int i = start;
    for (; i + 8 <= end; i += 8) {
        u64 p0 = epair2[i],     p1 = epair2[i + 1];
        u64 p2 = epair2[i + 2], p3 = epair2[i + 3];
        u64 p4 = epair2[i + 4], p5 = epair2[i + 5];
        u64 p6 = epair2[i + 6], p7 = epair2[i + 7];
        u32 c0 = RFL((u32)p0), b0 = RFL((u32)(p0 >> 32));
        u32 c1 = RFL((u32)p1), b1 = RFL((u32)(p1 >> 32));
        u32 c2 = RFL((u32)p2), b2 = RFL((u32)(p2 >> 32));
        u32 c3 = RFL((u32)p3), b3 = RFL((u32)(p3 >> 32));
        u32 c4 = RFL((u32)p4), b4 = RFL((u32)(p4 >> 32));
        u32 c5 = RFL((u32)p5), b5 = RFL((u32)(p5 >> 32));
        u32 c6 = RFL((u32)p6), b6 = RFL((u32)(p6 >> 32));
        u32 c7 = RFL((u32)p7), b7 = RFL((u32)(p7 >> 32));
        float g0 = bf2f(G[((size_t)c0 << 6) | lane]);
        float g1 = bf2f(G[((size_t)c1 << 6) | lane]);
        float g2 = bf2f(G[((size_t)c2 << 6) | lane]);
        float g3 = bf2f(G[((size_t)c3 << 6) | lane]);
        float g4 = bf2f(G[((size_t)c4 << 6) | lane]);
        float g5 = bf2f(G[((size_t)c5 << 6) | lane]);
        float g6 = bf2f(G[((size_t)c6 << 6) | lane]);
        float g7 = bf2f(G[((size_t)c7 << 6) | lane]);
        acc0 = fmaf(__uint_as_float(b0), g0, acc0);
        acc1 = fmaf(__uint_as_float(b1), g1, acc1);
        acc0 = fmaf(__uint_as_float(b2), g2, acc0);
        acc1 = fmaf(__uint_as_float(b3), g3, acc1);
        acc0 = fmaf(__uint_as_float(b4), g4, acc0);
        acc1 = fmaf(__uint_as_float(b5), g5, acc1);
        acc0 = fmaf(__uint_as_float(b6), g6, acc0);
        acc1 = fmaf(__uint_as_float(b7), g7, acc1);
    }
    for (; i < end; ++i) {
        u64 p = epair2[i];
        u32 c = RFL((u32)p), b = RFL((u32)(p >> 32));
        acc0 = fmaf(__uint_as_float(b), bf2f(G[((size_t)c << 6) | lane]), acc0);
    }
    float o = acc0 + acc1 + bias[lane];

    float s = o;
#pragma unroll
    for (int off = 32; off; off >>= 1) s += __shfl_xor(s, off);
    float mu = s * 0.015625f;
    float dv = o - mu;
    float vs = dv * dv;
#pragma unroll
    for (int off = 32; off; off >>= 1) vs += __shfl_xor(vs, off);
    float inv = rsqrtf(vs * 0.015625f + 1e-5f);
    out[((size_t)n << 6) + lane] = dv * inv * gamma[lane] + beta[lane];
}

extern "C" void kernel_launch(void* const* d_in, const int* in_sizes, int n_in,
                              void* d_out, int out_size, void* d_ws, size_t ws_size,
                              hipStream_t stream) {
    const float* feat  = (const float*)d_in[0];
    // d_in[1] = feat_ori: dead code in reference, unused
    const int*   row   = (const int*)d_in[2];
    const int*   col   = (const int*)d_in[3];
    const float* vals  = (const float*)d_in[4];
    const float* W     = (const float*)d_in[5];
    const float* bias  = (const float*)d_in[6];
    const float* gamma = (const float*)d_in[7];
    const float* beta  = (const float*)d_in[8];
    float* out = (float*)d_out;

    const int D = 64;
    int N = in_sizes[0] / D;   // 100000 -> NBK = 1563 <= MAXBK
    int E = in_sizes[2];

    int NBK = (N + 63) / 64;
    int CH  = ((E + GRID - 1) / GRID + 3) & ~3;   // edges per block, mult of 4

    // ws layout (aliased, ~26 MB total - same footprint as proven R6):
    //   Region A: G (bf16, N*128 B) / epair1 (E*8) - epair1 dead before P5.
    //   Region B: epair2 (E*8); hist2d (NBK*GRID*4 <= 6.4MB) at its front -
    //             hist2d dead (last read P3) before P4 writes epair2.
    //   Region C: btot (NBK), bbase (NBK+1), offs2 (N+1), bar (1).
    char* ws = (char*)d_ws;
    u16*   G      = (u16*)ws;
    u64*   epair1 = (u64*)ws;
    size_t sizeA  = (size_t)N * 128;
    if ((size_t)E * 8 > sizeA) sizeA = (size_t)E * 8;
    size_t boffB  = (sizeA + 255) & ~(size_t)255;
    u64*   epair2 = (u64*)(ws + boffB);
    u32*   hist2d = (u32*)(ws + boffB);
    size_t boffC  = boffB + (((size_t)E * 8 + 255) & ~(size_t)255);
    u32*   btot   = (u32*)(ws + boffC);
    u32*   bbase  = btot + NBK;          // NBK+1 entries
    u32*   offs2  = bbase + NBK + 1;     // N+1 entries
    u32*   bar    = offs2 + N + 1;       // 1 entry

    hipMemsetAsync(bar, 0, 4, stream);
    k_mega<<<GRID, 256, 0, stream>>>(feat, row, col, vals, W,
                                     G, epair1, epair2, hist2d, btot, bbase,
                                     offs2, bar, N, E, NBK, CH);
    k_node<<<(N + 3) / 4, 256, 0, stream>>>(G, epair2, offs2,
                                            bias, gamma, beta, out, N);
}

// Round 8
// 162.184 us; speedup vs baseline: 7.7955x; 7.7955x over previous
//
#include <hip/hip_runtime.h>

// SGC-Res: out = LayerNorm( (A @ feat) @ W^T + b )
// Identity: (A @ F) @ W^T = A @ (F @ W^T) = A @ G  (G in bf16).
// R8 pipeline (back to multi-kernel; R7's grid barriers cost ~200us each):
//   k_bhist:  per-block LDS histogram over row-buckets (64 rows/bkt)
//   k_bscan:  per-bucket exclusive scan of hist2d column across blocks
//   k_scanb2: exclusive scan of bucket totals -> bbase[]
//   k_bscat:  bucket-ordered scatter: epair1 = (lrow|col, val), plain stores
//   k_gemm:   G(bf16) = F @ W^T   (G overwrites hist2d region - dead by then)
//   k_node2:  one block per bucket: LDS-sort bucket edges by local row
//             (u32 LDS hist + wave scan + rank scatter), then per-wave
//             register-accumulate rows + fused bias + LayerNorm + store.
//             (replaces R6's k_regroup + epair2 global round-trip)

typedef unsigned int u32;
typedef unsigned short u16;
typedef unsigned long long u64;
#define RFL(x) __builtin_amdgcn_readfirstlane(x)

#define EPB 2048    // edges per binning block (8 per thread)
#define MAXBK 2048  // bucket count capacity in LDS (N <= 131072)
#define CAP 2048    // per-bucket edge capacity in k_node2 LDS

__device__ __forceinline__ float bf2f(u16 v) {
    return __uint_as_float((u32)v << 16);
}
__device__ __forceinline__ u16 f2bf(float f) {
    u32 b = __float_as_uint(f);
    return (u16)((b + 0x7FFFu + ((b >> 16) & 1u)) >> 16);  // RNE
}

__global__ __launch_bounds__(256) void k_bhist(const int* __restrict__ row,
                                               u32* __restrict__ hist2d,
                                               int E, int NBK) {
    __shared__ u32 cnt[MAXBK];
    for (int i = threadIdx.x; i < NBK; i += 256) cnt[i] = 0;
    __syncthreads();
    int e0 = blockIdx.x * EPB;
#pragma unroll
    for (int j = 0; j < EPB / 256; ++j) {
        int e = e0 + j * 256 + threadIdx.x;
        if (e < E) atomicAdd(&cnt[(u32)row[e] >> 6], 1u);  // LDS u32, no rtn
    }
    __syncthreads();
    u32* dst = hist2d + (size_t)blockIdx.x * NBK;
    for (int i = threadIdx.x; i < NBK; i += 256) dst[i] = cnt[i];
}

__device__ __forceinline__ u32 blk_scan256(u32 v, u32* wsum, u32& total) {
    int lane = threadIdx.x & 63, wid = threadIdx.x >> 6;
    u32 incl = v;
#pragma unroll
    for (int o = 1; o < 64; o <<= 1) {
        u32 u = __shfl_up(incl, o);
        if (lane >= o) incl += u;
    }
    if (lane == 63) wsum[wid] = incl;
    __syncthreads();
    u32 woff = 0;
    for (int w = 0; w < wid; ++w) woff += wsum[w];
    total = wsum[0] + wsum[1] + wsum[2] + wsum[3];
    __syncthreads();
    return woff + incl - v;  // exclusive prefix
}

__global__ __launch_bounds__(256) void k_bscan(u32* __restrict__ hist2d,
                                               u32* __restrict__ btot,
                                               int NBLK, int NBK) {
    __shared__ u32 wsum[4];
    int bkt = blockIdx.x;
    u32 carry = 0;
    for (int r = 0; r < NBLK; r += 256) {
        int blk = r + threadIdx.x;
        u32 v = (blk < NBLK) ? hist2d[(size_t)blk * NBK + bkt] : 0;
        u32 tot;
        u32 ex = blk_scan256(v, wsum, tot);
        if (blk < NBLK) hist2d[(size_t)blk * NBK + bkt] = ex + carry;
        carry += tot;
    }
    if (threadIdx.x == 0) btot[bkt] = carry;
}

__global__ __launch_bounds__(256) void k_scanb2(const u32* __restrict__ btot,
                                                u32* __restrict__ bbase,
                                                int NBK, int E) {
    __shared__ u32 wsum[4];
    u32 carry = 0;
    for (int r = 0; r < NBK; r += 256) {
        int i = r + threadIdx.x;
        u32 v = (i < NBK) ? btot[i] : 0;
        u32 tot;
        u32 ex = blk_scan256(v, wsum, tot);
        if (i < NBK) bbase[i] = ex + carry;
        carry += tot;
    }
    if (threadIdx.x == 0) bbase[NBK] = (u32)E;
}

__global__ __launch_bounds__(256) void k_bscat(const int* __restrict__ row,
                                               const int* __restrict__ col,
                                               const float* __restrict__ vals,
                                               const u32* __restrict__ hist2d,
                                               const u32* __restrict__ bbase,
                                               u64* __restrict__ epair1,
                                               int E, int NBK) {
    __shared__ u32 lbase[MAXBK];
    __shared__ u32 lcnt[MAXBK];
    const u32* hrow = hist2d + (size_t)blockIdx.x * NBK;
    for (int i = threadIdx.x; i < NBK; i += 256) {
        lbase[i] = bbase[i] + hrow[i];
        lcnt[i] = 0;
    }
    __syncthreads();
    int e0 = blockIdx.x * EPB;
#pragma unroll
    for (int j = 0; j < EPB / 256; ++j) {
        int e = e0 + j * 256 + threadIdx.x;
        if (e < E) {
            u32 r = (u32)row[e];
            u32 bkt = r >> 6;
            u32 lrank = atomicAdd(&lcnt[bkt], 1u);      // LDS u32 rtn, fast
            u32 pos = lbase[bkt] + lrank;
            u32 meta = (u32)col[e] | ((r & 63u) << 26); // col < 2^26
            epair1[pos] = (u64)meta | ((u64)__float_as_uint(vals[e]) << 32);
        }
    }
}

// Dense G(bf16) = F @ W^T. 256 thr = 4 waves, 64 nodes/block; W in VGPRs.
__global__ __launch_bounds__(256) void k_gemm(const float* __restrict__ feat,
                                              const float* __restrict__ W,
                                              u16* __restrict__ G, int N) {
    __shared__ float fs[4096];
    int lane = threadIdx.x & 63, wid = threadIdx.x >> 6;
    int n0 = blockIdx.x * 64;
    int valid = N - n0; if (valid > 64) valid = 64;
    int elems = valid * 64;
    for (int idx = threadIdx.x * 4; idx < elems; idx += 1024)
        *reinterpret_cast<float4*>(&fs[idx]) =
            *reinterpret_cast<const float4*>(&feat[(size_t)n0 * 64 + idx]);
    float wr[64];
#pragma unroll
    for (int d4 = 0; d4 < 16; ++d4) {
        float4 w4 = *reinterpret_cast<const float4*>(&W[lane * 64 + d4 * 4]);
        wr[d4 * 4 + 0] = w4.x; wr[d4 * 4 + 1] = w4.y;
        wr[d4 * 4 + 2] = w4.z; wr[d4 * 4 + 3] = w4.w;
    }
    __syncthreads();
    for (int j = 0; j < 16; ++j) {
        int r = wid * 16 + j;
        if (r >= valid) break;
        float o = 0.f;
#pragma unroll
        for (int d4 = 0; d4 < 16; ++d4) {
            float4 h4 = *reinterpret_cast<const float4*>(&fs[r * 64 + d4 * 4]);
            o = fmaf(h4.x, wr[d4 * 4 + 0], o);
            o = fmaf(h4.y, wr[d4 * 4 + 1], o);
            o = fmaf(h4.z, wr[d4 * 4 + 2], o);
            o = fmaf(h4.w, wr[d4 * 4 + 3], o);
        }
        G[(size_t)(n0 + r) * 64 + lane] = f2bf(o);
    }
}

// One block per bucket: LDS-sort edges by local row, then per-wave rows with
// register accumulation + fused LayerNorm.  lane = class c.
__global__ __launch_bounds__(256) void k_node2(
    const u16* __restrict__ G, const u64* __restrict__ epair1,
    const u32* __restrict__ bbase, const float* __restrict__ bias,
    const float* __restrict__ gamma, const float* __restrict__ beta,
    float* __restrict__ out, int N)
{
    __shared__ u64 sp[CAP];
    __shared__ u32 cnt[64], base[64], cnt2[64];
    int tid = threadIdx.x, lane = tid & 63, wid = tid >> 6;
    int bkt = blockIdx.x;
    if (tid < 64) { cnt[tid] = 0; cnt2[tid] = 0; }
    __syncthreads();
    int s = RFL((int)bbase[bkt]);
    int t = RFL((int)bbase[bkt + 1]);
    int m = t - s;
    bool fits = (m <= CAP);

    // pass 1: count local rows (low word only)
    const u32* meta1 = (const u32*)epair1;
    for (int i = s + tid; i < t; i += 256)
        atomicAdd(&cnt[meta1[2 * (size_t)i] >> 26], 1u);
    __syncthreads();
    // wave 0: 64-lane exclusive scan of cnt -> base
    if (tid < 64) {
        u32 v = cnt[tid];
        u32 incl = v;
#pragma unroll
        for (int o = 1; o < 64; o <<= 1) {
            u32 u = __shfl_up(incl, o);
            if (tid >= o) incl += u;
        }
        base[tid] = incl - v;
    }
    __syncthreads();
    // pass 2: rank-scatter pairs into row-sorted LDS slots (low word = col)
    if (fits) {
        for (int i = s + tid; i < t; i += 256) {
            u64 p = epair1[i];
            u32 mm = (u32)p;
            u32 r = mm >> 26;
            u32 rank = atomicAdd(&cnt2[r], 1u);
            sp[base[r] + rank] = (p & 0xFFFFFFFF00000000ull) | (u64)(mm & 0x03FFFFFFu);
        }
    }
    __syncthreads();

    int rbase = bkt << 6;
    for (int j = 0; j < 16; ++j) {
        int r = wid * 16 + j;
        int n = rbase + r;
        if (n >= N) break;
        float acc0 = 0.f, acc1 = 0.f;
        if (fits) {
            int e0 = base[r], e1 = base[r] + cnt[r];
            int i = e0;
            for (; i + 8 <= e1; i += 8) {
                u64 p0 = sp[i],     p1 = sp[i + 1];
                u64 p2 = sp[i + 2], p3 = sp[i + 3];
                u64 p4 = sp[i + 4], p5 = sp[i + 5];
                u64 p6 = sp[i + 6], p7 = sp[i + 7];
                u32 c0 = RFL((u32)p0), b0 = RFL((u32)(p0 >> 32));
                u32 c1 = RFL((u32)p1), b1 = RFL((u32)(p1 >> 32));
                u32 c2 = RFL((u32)p2), b2 = RFL((u32)(p2 >> 32));
                u32 c3 = RFL((u32)p3), b3 = RFL((u32)(p3 >> 32));
                u32 c4 = RFL((u32)p4), b4 = RFL((u32)(p4 >> 32));
                u32 c5 = RFL((u32)p5), b5 = RFL((u32)(p5 >> 32));
                u32 c6 = RFL((u32)p6), b6 = RFL((u32)(p6 >> 32));
                u32 c7 = RFL((u32)p7), b7 = RFL((u32)(p7 >> 32));
                float g0 = bf2f(G[((size_t)c0 << 6) | lane]);
                float g1 = bf2f(G[((size_t)c1 << 6) | lane]);
                float g2 = bf2f(G[((size_t)c2 << 6) | lane]);
                float g3 = bf2f(G[((size_t)c3 << 6) | lane]);
                float g4 = bf2f(G[((size_t)c4 << 6) | lane]);
                float g5 = bf2f(G[((size_t)c5 << 6) | lane]);
                float g6 = bf2f(G[((size_t)c6 << 6) | lane]);
                float g7 = bf2f(G[((size_t)c7 << 6) | lane]);
                acc0 = fmaf(__uint_as_float(b0), g0, acc0);
                acc1 = fmaf(__uint_as_float(b1), g1, acc1);
                acc0 = fmaf(__uint_as_float(b2), g2, acc0);
                acc1 = fmaf(__uint_as_float(b3), g3, acc1);
                acc0 = fmaf(__uint_as_float(b4), g4, acc0);
                acc1 = fmaf(__uint_as_float(b5), g5, acc1);
                acc0 = fmaf(__uint_as_float(b6), g6, acc0);
                acc1 = fmaf(__uint_as_float(b7), g7, acc1);
            }
            for (; i < e1; ++i) {
                u64 p = sp[i];
                u32 c = RFL((u32)p), b = RFL((u32)(p >> 32));
                acc0 = fmaf(__uint_as_float(b), bf2f(G[((size_t)c << 6) | lane]), acc0);
            }
        } else {
            // overflow fallback (never expected): filter-scan the bucket
            for (int i = s; i < t; ++i) {
                u64 p = epair1[i];
                u32 mm = RFL((u32)p);
                if ((int)(mm >> 26) == r) {
                    u32 b = RFL((u32)(p >> 32));
                    acc0 = fmaf(__uint_as_float(b),
                                bf2f(G[((size_t)(mm & 0x03FFFFFFu) << 6) | lane]), acc0);
                }
            }
        }
        float o = acc0 + acc1 + bias[lane];

        float ssum = o;
#pragma unroll
        for (int off = 32; off; off >>= 1) ssum += __shfl_xor(ssum, off);
        float mu = ssum * 0.015625f;
        float dv = o - mu;
        float vs = dv * dv;
#pragma unroll
        for (int off = 32; off; off >>= 1) vs += __shfl_xor(vs, off);
        float inv = rsqrtf(vs * 0.015625f + 1e-5f);
        out[((size_t)n << 6) + lane] = dv * inv * gamma[lane] + beta[lane];
    }
}

extern "C" void kernel_launch(void* const* d_in, const int* in_sizes, int n_in,
                              void* d_out, int out_size, void* d_ws, size_t ws_size,
                              hipStream_t stream) {
    const float* feat  = (const float*)d_in[0];
    // d_in[1] = feat_ori: dead code in reference, unused
    const int*   row   = (const int*)d_in[2];
    const int*   col   = (const int*)d_in[3];
    const float* vals  = (const float*)d_in[4];
    const float* W     = (const float*)d_in[5];
    const float* bias  = (const float*)d_in[6];
    const float* gamma = (const float*)d_in[7];
    const float* beta  = (const float*)d_in[8];
    float* out = (float*)d_out;

    const int D = 64;
    int N = in_sizes[0] / D;   // 100000 -> NBK = 1563 <= MAXBK
    int E = in_sizes[2];

    int NBK  = (N + 63) / 64;
    int NBLK = (E + EPB - 1) / EPB;

    // ws layout (aliased):
    //   Region A: G (bf16, N*128 B).  hist2d (NBLK*NBK*4) shares it - hist2d
    //             is last read by k_bscat, dead before k_gemm writes G.
    //   Region B: epair1 (E*8) - live until k_node2.  NOT aliased with G.
    //   Region C: btot (NBK), bbase (NBK+1).
    char* ws = (char*)d_ws;
    u16*   G      = (u16*)ws;
    u32*   hist2d = (u32*)ws;
    size_t sizeA  = (size_t)N * 128;
    size_t hsize  = (size_t)NBLK * NBK * 4;
    if (hsize > sizeA) sizeA = hsize;
    size_t boffB  = (sizeA + 255) & ~(size_t)255;
    u64*   epair1 = (u64*)(ws + boffB);
    size_t boffC  = boffB + (((size_t)E * 8 + 255) & ~(size_t)255);
    u32*   btot   = (u32*)(ws + boffC);
    u32*   bbase  = btot + NBK;          // NBK+1 entries

    k_bhist <<<NBLK, 256, 0, stream>>>(row, hist2d, E, NBK);
    k_bscan <<<NBK, 256, 0, stream>>>(hist2d, btot, NBLK, NBK);
    k_scanb2<<<1, 256, 0, stream>>>(btot, bbase, NBK, E);
    k_bscat <<<NBLK, 256, 0, stream>>>(row, col, vals, hist2d, bbase,
                                       epair1, E, NBK);
    k_gemm  <<<(N + 63) / 64, 256, 0, stream>>>(feat, W, G, N);
    k_node2 <<<NBK, 256, 0, stream>>>(G, epair1, bbase, bias, gamma, beta,
                                      out, N);
}

// Round 9
// 130.180 us; speedup vs baseline: 9.7120x; 1.2458x over previous
//
#include <hip/hip_runtime.h>

// SGC-Res: out = LayerNorm( (A @ feat) @ W^T + b )
// Identity: (A @ F) @ W^T = A @ (F @ W^T) = A @ G  (G in bf16).
// R9: NBLK=64 binning blocks (16 edges/bucket/block -> scatter writes are
// ~128B contiguous per bucket: no write-allocate amplification; hist2d is
// 0.4 MB, L2-hot).  gemm fused into the scatter launch (independent work,
// overlaps scatter latency).  Pipeline:
//   k_bhist:    per-block LDS histogram over row-buckets (64 rows/bkt)
//   k_bscan:    per-bucket exclusive scan of hist2d column across blocks
//   k_scanb2:   exclusive scan of bucket totals -> bbase[]
//   k_scatgemm: blocks [0,NBLK): bucket-ordered scatter -> epair1
//               blocks [NBLK,..): G(bf16) = F @ W^T
//   k_node2:    one block per bucket: LDS-sort by local row, per-wave
//               register-accumulate + fused bias + LayerNorm + store.

typedef unsigned int u32;
typedef unsigned short u16;
typedef unsigned long long u64;
#define RFL(x) __builtin_amdgcn_readfirstlane(x)

#define NBLKC 64    // binning blocks
#define MAXBK 2048  // bucket count capacity in LDS (N <= 131072)
#define CAP 2048    // per-bucket edge capacity in k_node2 LDS

__device__ __forceinline__ float bf2f(u16 v) {
    return __uint_as_float((u32)v << 16);
}
__device__ __forceinline__ u16 f2bf(float f) {
    u32 b = __float_as_uint(f);
    return (u16)((b + 0x7FFFu + ((b >> 16) & 1u)) >> 16);  // RNE
}

__global__ __launch_bounds__(256) void k_bhist(const int* __restrict__ row,
                                               u32* __restrict__ hist2d,
                                               int E, int NBK, int CH) {
    __shared__ u32 cnt[MAXBK];
    int tid = threadIdx.x;
    for (int i = tid; i < NBK; i += 256) cnt[i] = 0;
    __syncthreads();
    int e0 = blockIdx.x * CH;                 // CH mult of 4
    int e1 = e0 + CH; if (e1 > E) e1 = E;
    int ev = e1 & ~3;
    for (int i = e0 + tid * 4; i < ev; i += 1024) {
        int4 r = *reinterpret_cast<const int4*>(&row[i]);
        atomicAdd(&cnt[(u32)r.x >> 6], 1u);
        atomicAdd(&cnt[(u32)r.y >> 6], 1u);
        atomicAdd(&cnt[(u32)r.z >> 6], 1u);
        atomicAdd(&cnt[(u32)r.w >> 6], 1u);
    }
    { int i = ev + tid; if (i < e1) atomicAdd(&cnt[(u32)row[i] >> 6], 1u); }
    __syncthreads();
    u32* dst = hist2d + (size_t)blockIdx.x * NBK;
    for (int i = tid; i < NBK; i += 256) dst[i] = cnt[i];
}

__device__ __forceinline__ u32 blk_scan256(u32 v, u32* wsum, u32& total) {
    int lane = threadIdx.x & 63, wid = threadIdx.x >> 6;
    u32 incl = v;
#pragma unroll
    for (int o = 1; o < 64; o <<= 1) {
        u32 u = __shfl_up(incl, o);
        if (lane >= o) incl += u;
    }
    if (lane == 63) wsum[wid] = incl;
    __syncthreads();
    u32 woff = 0;
    for (int w = 0; w < wid; ++w) woff += wsum[w];
    total = wsum[0] + wsum[1] + wsum[2] + wsum[3];
    __syncthreads();
    return woff + incl - v;  // exclusive prefix
}

__global__ __launch_bounds__(256) void k_bscan(u32* __restrict__ hist2d,
                                               u32* __restrict__ btot,
                                               int NBLK, int NBK) {
    __shared__ u32 wsum[4];
    int bkt = blockIdx.x;
    u32 carry = 0;
    for (int r = 0; r < NBLK; r += 256) {
        int blk = r + threadIdx.x;
        u32 v = (blk < NBLK) ? hist2d[(size_t)blk * NBK + bkt] : 0;
        u32 tot;
        u32 ex = blk_scan256(v, wsum, tot);
        if (blk < NBLK) hist2d[(size_t)blk * NBK + bkt] = ex + carry;
        carry += tot;
    }
    if (threadIdx.x == 0) btot[bkt] = carry;
}

__global__ __launch_bounds__(256) void k_scanb2(const u32* __restrict__ btot,
                                                u32* __restrict__ bbase,
                                                int NBK, int E) {
    __shared__ u32 wsum[4];
    u32 carry = 0;
    for (int r = 0; r < NBK; r += 256) {
        int i = r + threadIdx.x;
        u32 v = (i < NBK) ? btot[i] : 0;
        u32 tot;
        u32 ex = blk_scan256(v, wsum, tot);
        if (i < NBK) bbase[i] = ex + carry;
        carry += tot;
    }
    if (threadIdx.x == 0) bbase[NBK] = (u32)E;
}

// Fused: blocks [0,NBLK) scatter edges; blocks [NBLK, NBLK+NG) compute G.
__global__ __launch_bounds__(256) void k_scatgemm(
    const int* __restrict__ row, const int* __restrict__ col,
    const float* __restrict__ vals, const u32* __restrict__ hist2d,
    const u32* __restrict__ bbase, u64* __restrict__ epair1,
    const float* __restrict__ feat, const float* __restrict__ W,
    u16* __restrict__ G, int E, int N, int NBK, int NBLK, int CH)
{
    __shared__ __align__(16) u32 smem[4096];  // 16 KB union
    int tid = threadIdx.x;
    if ((int)blockIdx.x < NBLK) {
        // ---------------- scatter path ----------------
        u32* lbase = smem;         // NBK
        u32* lcnt  = smem + NBK;   // NBK  (2*MAXBK*4 = 16 KB max)
        int blk = blockIdx.x;
        const u32* hrow = hist2d + (size_t)blk * NBK;
        for (int i = tid; i < NBK; i += 256) {
            lbase[i] = bbase[i] + hrow[i];
            lcnt[i] = 0;
        }
        __syncthreads();
        int e0 = blk * CH;
        int e1 = e0 + CH; if (e1 > E) e1 = E;
        int ev = e1 & ~3;
        for (int i = e0 + tid * 4; i < ev; i += 1024) {
            int4 r = *reinterpret_cast<const int4*>(&row[i]);
            int4 c = *reinterpret_cast<const int4*>(&col[i]);
            float4 v = *reinterpret_cast<const float4*>(&vals[i]);
            u32 k0 = (u32)r.x >> 6, k1 = (u32)r.y >> 6;
            u32 k2 = (u32)r.z >> 6, k3 = (u32)r.w >> 6;
            u32 q0 = atomicAdd(&lcnt[k0], 1u);
            u32 q1 = atomicAdd(&lcnt[k1], 1u);
            u32 q2 = atomicAdd(&lcnt[k2], 1u);
            u32 q3 = atomicAdd(&lcnt[k3], 1u);
            epair1[lbase[k0] + q0] = (u64)((u32)c.x | (((u32)r.x & 63u) << 26))
                                   | ((u64)__float_as_uint(v.x) << 32);
            epair1[lbase[k1] + q1] = (u64)((u32)c.y | (((u32)r.y & 63u) << 26))
                                   | ((u64)__float_as_uint(v.y) << 32);
            epair1[lbase[k2] + q2] = (u64)((u32)c.z | (((u32)r.z & 63u) << 26))
                                   | ((u64)__float_as_uint(v.z) << 32);
            epair1[lbase[k3] + q3] = (u64)((u32)c.w | (((u32)r.w & 63u) << 26))
                                   | ((u64)__float_as_uint(v.w) << 32);
        }
        {
            int i = ev + tid;
            if (i < e1) {
                u32 r = (u32)row[i];
                u32 k = r >> 6;
                u32 q = atomicAdd(&lcnt[k], 1u);
                epair1[lbase[k] + q] = (u64)((u32)col[i] | ((r & 63u) << 26))
                                     | ((u64)__float_as_uint(vals[i]) << 32);
            }
        }
    } else {
        // ---------------- gemm path: G(bf16) = F @ W^T ----------------
        float* fs = (float*)smem;   // 4096 floats
        int lane = tid & 63, wid = tid >> 6;
        int n0 = ((int)blockIdx.x - NBLK) * 64;
        int valid = N - n0; if (valid > 64) valid = 64;
        int elems = valid * 64;
        for (int idx = tid * 4; idx < elems; idx += 1024)
            *reinterpret_cast<float4*>(&fs[idx]) =
                *reinterpret_cast<const float4*>(&feat[(size_t)n0 * 64 + idx]);
        float wr[64];
#pragma unroll
        for (int d4 = 0; d4 < 16; ++d4) {
            float4 w4 = *reinterpret_cast<const float4*>(&W[lane * 64 + d4 * 4]);
            wr[d4 * 4 + 0] = w4.x; wr[d4 * 4 + 1] = w4.y;
            wr[d4 * 4 + 2] = w4.z; wr[d4 * 4 + 3] = w4.w;
        }
        __syncthreads();
        for (int j = 0; j < 16; ++j) {
            int r = wid * 16 + j;
            if (r >= valid) break;
            float o = 0.f;
#pragma unroll
            for (int d4 = 0; d4 < 16; ++d4) {
                float4 h4 = *reinterpret_cast<const float4*>(&fs[r * 64 + d4 * 4]);
                o = fmaf(h4.x, wr[d4 * 4 + 0], o);
                o = fmaf(h4.y, wr[d4 * 4 + 1], o);
                o = fmaf(h4.z, wr[d4 * 4 + 2], o);
                o = fmaf(h4.w, wr[d4 * 4 + 3], o);
            }
            G[(size_t)(n0 + r) * 64 + lane] = f2bf(o);
        }
    }
}

// One block per bucket: LDS-sort edges by local row, then per-wave rows with
// register accumulation + fused LayerNorm.  lane = class c.  (R8-proven.)
__global__ __launch_bounds__(256) void k_node2(
    const u16* __restrict__ G, const u64* __restrict__ epair1,
    const u32* __restrict__ bbase, const float* __restrict__ bias,
    const float* __restrict__ gamma, const float* __restrict__ beta,
    float* __restrict__ out, int N)
{
    __shared__ u64 sp[CAP];
    __shared__ u32 cnt[64], base[64], cnt2[64];
    int tid = threadIdx.x, lane = tid & 63, wid = tid >> 6;
    int bkt = blockIdx.x;
    if (tid < 64) { cnt[tid] = 0; cnt2[tid] = 0; }
    __syncthreads();
    int s = RFL((int)bbase[bkt]);
    int t = RFL((int)bbase[bkt + 1]);
    int m = t - s;
    bool fits = (m <= CAP);

    const u32* meta1 = (const u32*)epair1;
    for (int i = s + tid; i < t; i += 256)
        atomicAdd(&cnt[meta1[2 * (size_t)i] >> 26], 1u);
    __syncthreads();
    if (tid < 64) {
        u32 v = cnt[tid];
        u32 incl = v;
#pragma unroll
        for (int o = 1; o < 64; o <<= 1) {
            u32 u = __shfl_up(incl, o);
            if (tid >= o) incl += u;
        }
        base[tid] = incl - v;
    }
    __syncthreads();
    if (fits) {
        for (int i = s + tid; i < t; i += 256) {
            u64 p = epair1[i];
            u32 mm = (u32)p;
            u32 r = mm >> 26;
            u32 rank = atomicAdd(&cnt2[r], 1u);
            sp[base[r] + rank] = (p & 0xFFFFFFFF00000000ull) | (u64)(mm & 0x03FFFFFFu);
        }
    }
    __syncthreads();

    int rbase = bkt << 6;
    for (int j = 0; j < 16; ++j) {
        int r = wid * 16 + j;
        int n = rbase + r;
        if (n >= N) break;
        float acc0 = 0.f, acc1 = 0.f;
        if (fits) {
            int e0 = base[r], e1 = base[r] + cnt[r];
            int i = e0;
            for (; i + 8 <= e1; i += 8) {
                u64 p0 = sp[i],     p1 = sp[i + 1];
                u64 p2 = sp[i + 2], p3 = sp[i + 3];
                u64 p4 = sp[i + 4], p5 = sp[i + 5];
                u64 p6 = sp[i + 6], p7 = sp[i + 7];
                u32 c0 = RFL((u32)p0), b0 = RFL((u32)(p0 >> 32));
                u32 c1 = RFL((u32)p1), b1 = RFL((u32)(p1 >> 32));
                u32 c2 = RFL((u32)p2), b2 = RFL((u32)(p2 >> 32));
                u32 c3 = RFL((u32)p3), b3 = RFL((u32)(p3 >> 32));
                u32 c4 = RFL((u32)p4), b4 = RFL((u32)(p4 >> 32));
                u32 c5 = RFL((u32)p5), b5 = RFL((u32)(p5 >> 32));
                u32 c6 = RFL((u32)p6), b6 = RFL((u32)(p6 >> 32));
                u32 c7 = RFL((u32)p7), b7 = RFL((u32)(p7 >> 32));
                float g0 = bf2f(G[((size_t)c0 << 6) | lane]);
                float g1 = bf2f(G[((size_t)c1 << 6) | lane]);
                float g2 = bf2f(G[((size_t)c2 << 6) | lane]);
                float g3 = bf2f(G[((size_t)c3 << 6) | lane]);
                float g4 = bf2f(G[((size_t)c4 << 6) | lane]);
                float g5 = bf2f(G[((size_t)c5 << 6) | lane]);
                float g6 = bf2f(G[((size_t)c6 << 6) | lane]);
                float g7 = bf2f(G[((size_t)c7 << 6) | lane]);
                acc0 = fmaf(__uint_as_float(b0), g0, acc0);
                acc1 = fmaf(__uint_as_float(b1), g1, acc1);
                acc0 = fmaf(__uint_as_float(b2), g2, acc0);
                acc1 = fmaf(__uint_as_float(b3), g3, acc1);
                acc0 = fmaf(__uint_as_float(b4), g4, acc0);
                acc1 = fmaf(__uint_as_float(b5), g5, acc1);
                acc0 = fmaf(__uint_as_float(b6), g6, acc0);
                acc1 = fmaf(__uint_as_float(b7), g7, acc1);
            }
            for (; i < e1; ++i) {
                u64 p = sp[i];
                u32 c = RFL((u32)p), b = RFL((u32)(p >> 32));
                acc0 = fmaf(__uint_as_float(b), bf2f(G[((size_t)c << 6) | lane]), acc0);
            }
        } else {
            for (int i = s; i < t; ++i) {
                u64 p = epair1[i];
                u32 mm = RFL((u32)p);
                if ((int)(mm >> 26) == r) {
                    u32 b = RFL((u32)(p >> 32));
                    acc0 = fmaf(__uint_as_float(b),
                                bf2f(G[((size_t)(mm & 0x03FFFFFFu) << 6) | lane]), acc0);
                }
            }
        }
        float o = acc0 + acc1 + bias[lane];

        float ssum = o;
#pragma unroll
        for (int off = 32; off; off >>= 1) ssum += __shfl_xor(ssum, off);
        float mu = ssum * 0.015625f;
        float dv = o - mu;
        float vs = dv * dv;
#pragma unroll
        for (int off = 32; off; off >>= 1) vs += __shfl_xor(vs, off);
        float inv = rsqrtf(vs * 0.015625f + 1e-5f);
        out[((size_t)n << 6) + lane] = dv * inv * gamma[lane] + beta[lane];
    }
}

extern "C" void kernel_launch(void* const* d_in, const int* in_sizes, int n_in,
                              void* d_out, int out_size, void* d_ws, size_t ws_size,
                              hipStream_t stream) {
    const float* feat  = (const float*)d_in[0];
    // d_in[1] = feat_ori: dead code in reference, unused
    const int*   row   = (const int*)d_in[2];
    const int*   col   = (const int*)d_in[3];
    const float* vals  = (const float*)d_in[4];
    const float* W     = (const float*)d_in[5];
    const float* bias  = (const float*)d_in[6];
    const float* gamma = (const float*)d_in[7];
    const float* beta  = (const float*)d_in[8];
    float* out = (float*)d_out;

    const int D = 64;
    int N = in_sizes[0] / D;   // 100000 -> NBK = 1563 <= MAXBK
    int E = in_sizes[2];

    int NBK  = (N + 63) / 64;
    int NBLK = NBLKC;
    int CH   = (((E + NBLK - 1) / NBLK) + 3) & ~3;   // edges/block, mult of 4
    int NG   = (N + 63) / 64;                        // gemm blocks

    // ws layout (no aliasing needed; hist2d is tiny now):
    //   G (bf16, N*128 B) | epair1 (E*8) | hist2d (NBLK*NBK*4) | btot | bbase
    char* ws = (char*)d_ws;
    u16*   G      = (u16*)ws;
    size_t off1   = (((size_t)N * 128) + 255) & ~(size_t)255;
    u64*   epair1 = (u64*)(ws + off1);
    size_t off2   = off1 + (((size_t)E * 8 + 255) & ~(size_t)255);
    u32*   hist2d = (u32*)(ws + off2);
    size_t off3   = off2 + (((size_t)NBLK * NBK * 4 + 255) & ~(size_t)255);
    u32*   btot   = (u32*)(ws + off3);
    u32*   bbase  = btot + NBK;          // NBK+1 entries

    k_bhist   <<<NBLK, 256, 0, stream>>>(row, hist2d, E, NBK, CH);
    k_bscan   <<<NBK, 256, 0, stream>>>(hist2d, btot, NBLK, NBK);
    k_scanb2  <<<1, 256, 0, stream>>>(btot, bbase, NBK, E);
    k_scatgemm<<<NBLK + NG, 256, 0, stream>>>(row, col, vals, hist2d, bbase,
                                              epair1, feat, W, G,
                                              E, N, NBK, NBLK, CH);
    k_node2   <<<NBK, 256, 0, stream>>>(G, epair1, bbase, bias, gamma, beta,
                                        out, N);
}